// Round 1
// baseline (265.534 us; speedup 1.0000x reference)
//
#include <hip/hip_runtime.h>

typedef __attribute__((ext_vector_type(8))) __bf16 bf16x8;
typedef __attribute__((ext_vector_type(8))) unsigned short ushort8;
typedef __attribute__((ext_vector_type(4))) float f32x4;

constexpr int B_ = 2, C_ = 32, NN = 64;
constexpr int PK = 3375;              // 15^3
constexpr int K_TOT = C_ * PK;        // 108000
constexpr int F_TOT = 1024;
constexpr int M_TOT = 128;            // B*N
constexpr int KSTEPS = K_TOT / 32;    // 3375

__device__ __forceinline__ unsigned short f2bf(float f) {
    unsigned int b = __builtin_bit_cast(unsigned int, f);
    b += 0x7FFFu + ((b >> 16) & 1u);      // round-to-nearest-even
    return (unsigned short)(b >> 16);
}

// ---------------- kernel 1: patch gather -> bf16 A[128][108000] ----------------
__global__ void extract_kernel(const float* __restrict__ x,
                               const int* __restrict__ cent,
                               unsigned short* __restrict__ A) {
    int m = blockIdx.x;            // 0..127  (b*64+n)
    int c = blockIdx.y;            // 0..31
    int b = m >> 6, n = m & 63;
    int cx = cent[(b * NN + n) * 3 + 0];
    int cy = cent[(b * NN + n) * 3 + 1];
    int cz = cent[(b * NN + n) * 3 + 2];
    int sx = max(cx - 7, 0), ex = min(cx + 8, 96);
    int sy = max(cy - 7, 0), ey = min(cy + 8, 96);
    int sz = max(cz - 7, 0), ez = min(cz + 8, 96);
    const float* xb = x + (size_t)(b * C_ + c) * (96 * 96 * 96);
    unsigned short* Arow = A + (size_t)m * K_TOT + (size_t)c * PK;
    for (int k = threadIdx.x; k < PK; k += blockDim.x) {
        int iz = k % 15;
        int t  = k / 15;
        int iy = t % 15;
        int ix = t / 15;
        int hx = sx + ix, wy = sy + iy, dz = sz + iz;
        float v = 0.0f;
        if (hx < ex && wy < ey && dz < ez)
            v = xb[(hx * 96 + wy) * 96 + dz];
        Arow[k] = f2bf(v);
    }
}

// ---------------- kernel 2: split-K GEMM, bf16 MFMA, fp32 partials ----------------
__global__ __launch_bounds__(512) void gemm_kernel(const unsigned short* __restrict__ A,
                                                   const float* __restrict__ W,
                                                   float* __restrict__ partial,
                                                   int CS) {
    __shared__ unsigned short wlds[32][130];   // [k][f], stride 130 kills bank conflicts
    int f0  = blockIdx.x * 128;                // 8 F-tiles of 128
    int s   = blockIdx.y;                      // K-chunk
    int st0 = s * CS;
    int st1 = min(st0 + CS, KSTEPS);

    int tid  = (int)threadIdx.x;
    int wave = tid >> 6, lane = tid & 63;
    int lrow = lane & 15, lgrp = lane >> 4;

    f32x4 acc[8];
#pragma unroll
    for (int i = 0; i < 8; ++i) acc[i] = (f32x4)(0.0f);

    int kl  = tid >> 4;            // 0..31  : W row this thread stages
    int fl8 = (tid & 15) << 3;     // 0..120 : 8-float group within the 128-col tile

    for (int st = st0; st < st1; ++st) {
        int k0 = st << 5;
        // --- stage W[k0+kl][f0+fl8 .. +7] -> LDS (fp32 -> bf16) ---
        {
            const float* src = W + (size_t)(k0 + kl) * F_TOT + f0 + fl8;
            f32x4 v0 = *reinterpret_cast<const f32x4*>(src);
            f32x4 v1 = *reinterpret_cast<const f32x4*>(src + 4);
            unsigned int* dst = reinterpret_cast<unsigned int*>(&wlds[kl][fl8]);
            dst[0] = (unsigned)f2bf(v0.x) | ((unsigned)f2bf(v0.y) << 16);
            dst[1] = (unsigned)f2bf(v0.z) | ((unsigned)f2bf(v0.w) << 16);
            dst[2] = (unsigned)f2bf(v1.x) | ((unsigned)f2bf(v1.y) << 16);
            dst[3] = (unsigned)f2bf(v1.z) | ((unsigned)f2bf(v1.w) << 16);
        }
        __syncthreads();

        // --- B fragment: W[k0 + 8*lgrp + j][f0 + wave*16 + lrow], j=0..7 ---
        ushort8 bt;
#pragma unroll
        for (int j = 0; j < 8; ++j)
            bt[j] = wlds[(lgrp << 3) + j][(wave << 4) + lrow];
        bf16x8 bfrag = __builtin_bit_cast(bf16x8, bt);

        // --- A fragments direct from global (bf16, contiguous K) + MFMA ---
        const unsigned short* Ap = A + (size_t)lrow * K_TOT + k0 + (lgrp << 3);
#pragma unroll
        for (int mt = 0; mt < 8; ++mt) {
            bf16x8 afrag = *reinterpret_cast<const bf16x8*>(Ap + (size_t)(mt * 16) * K_TOT);
            acc[mt] = __builtin_amdgcn_mfma_f32_16x16x32_bf16(afrag, bfrag, acc[mt], 0, 0, 0);
        }
        __syncthreads();
    }

    // --- write partials: D row = lgrp*4 + r, col = lrow ---
    float* pout = partial + (size_t)s * (M_TOT * F_TOT);
    int f = f0 + (wave << 4) + lrow;
#pragma unroll
    for (int mt = 0; mt < 8; ++mt) {
        int mbase = mt * 16 + lgrp * 4;
#pragma unroll
        for (int r = 0; r < 4; ++r)
            pout[(size_t)(mbase + r) * F_TOT + f] = acc[mt][r];
    }
}

// ---------------- kernel 3: split-K reduce + bias ----------------
__global__ void reduce_kernel(const float* __restrict__ partial,
                              const float* __restrict__ bias,
                              float* __restrict__ out, int S) {
    int i = blockIdx.x * blockDim.x + threadIdx.x;
    if (i >= M_TOT * F_TOT) return;
    float a = bias[i & (F_TOT - 1)];
    for (int s = 0; s < S; ++s)
        a += partial[(size_t)s * (M_TOT * F_TOT) + i];
    out[i] = a;
}

extern "C" void kernel_launch(void* const* d_in, const int* in_sizes, int n_in,
                              void* d_out, int out_size, void* d_ws, size_t ws_size,
                              hipStream_t stream) {
    const float* x    = (const float*)d_in[0];
    const int*   cent = (const int*)d_in[1];
    const float* W    = (const float*)d_in[2];
    const float* bias = (const float*)d_in[3];
    float* out = (float*)d_out;

    unsigned short* A = (unsigned short*)d_ws;
    size_t A_bytes = (size_t)M_TOT * K_TOT * 2;                 // 27,648,000 (256B-aligned)
    float* partial = (float*)((char*)d_ws + A_bytes);

    size_t avail = ws_size > A_bytes ? ws_size - A_bytes : 0;
    int S = (int)(avail / ((size_t)M_TOT * F_TOT * 4));
    if (S > 64) S = 64;
    if (S < 1)  S = 1;
    int CS = (KSTEPS + S - 1) / S;
    S = (KSTEPS + CS - 1) / CS;   // drop empty chunks

    extract_kernel<<<dim3(M_TOT, C_), 256, 0, stream>>>(x, cent, A);
    gemm_kernel<<<dim3(8, S), 512, 0, stream>>>(A, W, partial, CS);
    reduce_kernel<<<dim3((M_TOT * F_TOT) / 256), 256, 0, stream>>>(partial, bias, out, S);
}